// Round 11
// baseline (687.389 us; speedup 1.0000x reference)
//
#include <hip/hip_runtime.h>
#include <math.h>

#define NN 100000
#define NE 1600000
#define NBLK_SCAN 391   // ceil(NN/256)

__device__ __forceinline__ float lrelu(float x) { return x > 0.f ? x : 0.2f * x; }

// ---- init: zero degree ------------------------------------------------
__global__ __launch_bounds__(256) void k_init(int* __restrict__ deg) {
    int i = blockIdx.x * 256 + threadIdx.x;
    if (i < NN) deg[i] = 0;
}

// ---- CSR build: histogram (captures position), scan, atomic-free fill --
// 2 edges per thread (NE even, grid exact: 3125*256*2 = 1.6M)
__global__ __launch_bounds__(256) void k_deg(const int* __restrict__ dst, int* __restrict__ deg,
                                             int* __restrict__ pos) {
    unsigned e = (blockIdx.x * 256 + threadIdx.x) * 2u;
    int2 d2 = *(const int2*)(dst + e);
    int p0 = atomicAdd(&deg[d2.x], 1);
    int p1 = atomicAdd(&deg[d2.y], 1);
    *(int2*)(pos + e) = make_int2(p0, p1);
}

__global__ __launch_bounds__(256) void k_scan1(const int* __restrict__ deg,
                                               int* __restrict__ row_ptr, int* __restrict__ bsum) {
    __shared__ int sm[256];
    int t = threadIdx.x, i = blockIdx.x * 256 + t;
    int v = (i < NN) ? deg[i] : 0;
    sm[t] = v; __syncthreads();
#pragma unroll
    for (int off = 1; off < 256; off <<= 1) {
        int u = (t >= off) ? sm[t - off] : 0;
        __syncthreads();
        sm[t] += u;
        __syncthreads();
    }
    int incl = sm[t];
    if (i < NN) row_ptr[i] = incl - v;           // block-local exclusive
    if (t == 255) bsum[blockIdx.x] = incl;       // block total
}

__global__ __launch_bounds__(512) void k_scan2(int* __restrict__ bsum) {
    __shared__ int sm[512];
    int t = threadIdx.x;
    int v = (t < NBLK_SCAN) ? bsum[t] : 0;
    sm[t] = v; __syncthreads();
#pragma unroll
    for (int off = 1; off < 512; off <<= 1) {
        int u = (t >= off) ? sm[t - off] : 0;
        __syncthreads();
        sm[t] += u;
        __syncthreads();
    }
    if (t < NBLK_SCAN) bsum[t] = sm[t] - v;      // exclusive block prefix
}

__global__ __launch_bounds__(256) void k_scan3(int* __restrict__ row_ptr, const int* __restrict__ bsum) {
    int i = blockIdx.x * 256 + threadIdx.x;
    if (i < NN) row_ptr[i] += bsum[i >> 8];
    if (i == 0) row_ptr[NN] = NE;
}

// packed[i] = (src_node, ew_bits); atomic-free (pos captured in k_deg)
__global__ __launch_bounds__(256) void k_fill(const int* __restrict__ src, const int* __restrict__ dst,
                                              const float* __restrict__ ew,
                                              const int* __restrict__ row_ptr,
                                              const int* __restrict__ pos,
                                              int2* __restrict__ packed) {
    unsigned e = (blockIdx.x * 256 + threadIdx.x) * 2u;
    int2 s2 = *(const int2*)(src + e);
    int2 d2 = *(const int2*)(dst + e);
    float2 w2 = *(const float2*)(ew + e);
    int2 po = *(const int2*)(pos + e);
    packed[(unsigned)(row_ptr[d2.x] + po.x)] = make_int2(s2.x, __float_as_int(w2.x));
    packed[(unsigned)(row_ptr[d2.y] + po.y)] = make_int2(s2.y, __float_as_int(w2.y));
}

// ---- GEMM1 + fused layer-1 attention logits ---------------------------
__global__ __launch_bounds__(256) void k_gemm1(const float* __restrict__ x,
                                               const float* __restrict__ W,
                                               const float* __restrict__ asrc,
                                               const float* __restrict__ adst,
                                               float* __restrict__ h1,
                                               float* __restrict__ as1,
                                               float* __restrict__ ad1) {
    __shared__ float xs[128][64];   // xs[k][row]
    __shared__ float ws[128][64];   // ws[k][col]
    const int row0 = blockIdx.x * 64;
    const int col0 = blockIdx.y * 64;
    const int t = threadIdx.x;

    {   // x tile (zero-padded past NN)
        int row = t & 63;
        int grow = row0 + row;
        bool ok = grow < NN;
#pragma unroll
        for (int i = 0; i < 8; i++) {
            int kq = (t >> 6) + i * 4;
            float4 v = ok ? *(const float4*)(x + (size_t)grow * 128 + kq * 4)
                          : make_float4(0.f, 0.f, 0.f, 0.f);
            xs[kq * 4 + 0][row] = v.x;
            xs[kq * 4 + 1][row] = v.y;
            xs[kq * 4 + 2][row] = v.z;
            xs[kq * 4 + 3][row] = v.w;
        }
    }
    {   // W tile
#pragma unroll
        for (int i = 0; i < 8; i++) {
            int lin = t + i * 256;
            int kk = lin >> 4;
            int cq = lin & 15;
            float4 v = *(const float4*)(W + (size_t)kk * 128 + col0 + cq * 4);
            *(float4*)&ws[kk][cq * 4] = v;
        }
    }
    __syncthreads();

    const int tx = t & 15, ty = t >> 4;     // thread = rows ty*4..+3, cols tx*4..+3
    float acc[4][4] = {};
#pragma unroll 4
    for (int k = 0; k < 128; k++) {
        float4 a4 = *(const float4*)&xs[k][ty * 4];
        float4 b4 = *(const float4*)&ws[k][tx * 4];
        float a[4] = {a4.x, a4.y, a4.z, a4.w};
        float b[4] = {b4.x, b4.y, b4.z, b4.w};
#pragma unroll
        for (int i = 0; i < 4; i++)
#pragma unroll
            for (int j = 0; j < 4; j++)
                acc[i][j] = fmaf(a[i], b[j], acc[i][j]);
    }

    // store h1 tile
#pragma unroll
    for (int i = 0; i < 4; i++) {
        int r = row0 + ty * 4 + i;
        if (r < NN) {
            float4 v = make_float4(acc[i][0], acc[i][1], acc[i][2], acc[i][3]);
            *(float4*)(h1 + (size_t)r * 128 + col0 + tx * 4) = v;
        }
    }

    // fused attention logits: head = col0/32 + tx/8; reduce over 8-lane tx group
    const int head = (col0 >> 5) + (tx >> 3);
    const float4 avs = *(const float4*)(asrc + head * 32 + (tx & 7) * 4);
    const float4 avd = *(const float4*)(adst + head * 32 + (tx & 7) * 4);
#pragma unroll
    for (int i = 0; i < 4; i++) {
        float ps = acc[i][0] * avs.x + acc[i][1] * avs.y + acc[i][2] * avs.z + acc[i][3] * avs.w;
        float pd = acc[i][0] * avd.x + acc[i][1] * avd.y + acc[i][2] * avd.z + acc[i][3] * avd.w;
        ps += __shfl_xor(ps, 1); ps += __shfl_xor(ps, 2); ps += __shfl_xor(ps, 4);
        pd += __shfl_xor(pd, 1); pd += __shfl_xor(pd, 2); pd += __shfl_xor(pd, 4);
        int r = row0 + ty * 4 + i;
        if ((tx & 7) == 0 && r < NN) {
            as1[(size_t)r * 4 + head] = ps;
            ad1[(size_t)r * 4 + head] = pd;
        }
    }
}

// ---- layer1: two-pass segment softmax + gather (wave per node) --------
// Half-wave `half` owns edges beg+half, beg+half+2, ...; lane owns
// features fl*4..fl*4+3 (fl = lane&31, float4 = 16B/lane, head = fl>>3).
// Pass A: max over 4B as1 gathers.  Pass B: plain exp-sum + accumulate
// (no online rescale -> ~half the VALU ops of r7's ring loop).
__global__ __launch_bounds__(256) void k_msg1(const int* __restrict__ row_ptr,
                                              const int2* __restrict__ packed,
                                              const float* __restrict__ as1,
                                              const float* __restrict__ ad1,
                                              const float* __restrict__ h1,
                                              const float* __restrict__ b1,
                                              float* __restrict__ h2) {
    int gw = (blockIdx.x * 256 + threadIdx.x) >> 6;   // node id
    if (gw >= NN) return;
    const int lane = threadIdx.x & 63;
    const int half = lane >> 5;
    const int fl = lane & 31;
    const int h = fl >> 3;                            // head of this float4
    const float adv = ad1[(unsigned)gw * 4u + h];
    const int beg = row_ptr[gw], end = row_ptr[gw + 1];

    // pass A: segment max (cheap 4B gathers)
    float m = -INFINITY;
    for (int i = beg + half; i < end; i += 2) {
        unsigned s = (unsigned)packed[(unsigned)i].x;
        m = fmaxf(m, lrelu(as1[s * 4u + h] + adv));
    }
    float M = fmaxf(m, __shfl_xor(m, 32));            // full segment max

    // pass B: exp-sum + weighted feature accumulation
    float den = 0.f;
    float4 acc = make_float4(0.f, 0.f, 0.f, 0.f);
    for (int i = beg + half; i < end; i += 2) {
        int2 p = packed[(unsigned)i];
        unsigned s = (unsigned)p.x;
        float ex = __expf(lrelu(as1[s * 4u + h] + adv) - M);
        den += ex;
        float cw = ex * __int_as_float(p.y);
        float4 hv = *(const float4*)(h1 + s * 128u + fl * 4u);
        acc.x = fmaf(hv.x, cw, acc.x);
        acc.y = fmaf(hv.y, cw, acc.y);
        acc.z = fmaf(hv.z, cw, acc.z);
        acc.w = fmaf(hv.w, cw, acc.w);
    }
    den   += __shfl_xor(den, 32);
    acc.x += __shfl_xor(acc.x, 32);
    acc.y += __shfl_xor(acc.y, 32);
    acc.z += __shfl_xor(acc.z, 32);
    acc.w += __shfl_xor(acc.w, 32);
    if (half == 0) {
        float rden = 1.f / (den + 1e-16f);
        float4 bv = *(const float4*)(b1 + fl * 4);
        float4 v;
        v.x = fmaxf(acc.x * rden + bv.x, 0.f);
        v.y = fmaxf(acc.y * rden + bv.y, 0.f);
        v.z = fmaxf(acc.z * rden + bv.z, 0.f);
        v.w = fmaxf(acc.w * rden + bv.w, 0.f);
        *(float4*)(h2 + (unsigned)gw * 128u + fl * 4u) = v;
    }
}

// ---- GEMM2 + fused layer-2 attention logits ---------------------------
__global__ __launch_bounds__(256) void k_gemm2(const float* __restrict__ h2,
                                               const float* __restrict__ W2,
                                               const float* __restrict__ asrc,
                                               const float* __restrict__ adst,
                                               float* __restrict__ g2,
                                               float* __restrict__ as2,
                                               float* __restrict__ ad2) {
    __shared__ float xs[128][64];
    __shared__ float ws2[128 * 40];
    const int row0 = blockIdx.x * 64;
    const int t = threadIdx.x;
    {
        int row = t & 63;
        int grow = row0 + row;
        bool ok = grow < NN;
#pragma unroll
        for (int i = 0; i < 8; i++) {
            int kq = (t >> 6) + i * 4;
            float4 v = ok ? *(const float4*)(h2 + (size_t)grow * 128 + kq * 4)
                          : make_float4(0.f, 0.f, 0.f, 0.f);
            xs[kq * 4 + 0][row] = v.x;
            xs[kq * 4 + 1][row] = v.y;
            xs[kq * 4 + 2][row] = v.z;
            xs[kq * 4 + 3][row] = v.w;
        }
    }
    {
#pragma unroll
        for (int i = 0; i < 5; i++) {
            int lin = t + i * 256;
            *(float4*)&ws2[lin * 4] = *(const float4*)(W2 + lin * 4);
        }
    }
    __syncthreads();
    const int g = t & 3, r = t >> 2;          // 64 rows x 4 col-groups of 10
    float acc[10] = {};
#pragma unroll 4
    for (int k = 0; k < 128; k++) {
        float a = xs[k][r];
        const float* wb = &ws2[k * 40 + g * 10];
#pragma unroll
        for (int j = 0; j < 10; j++) acc[j] = fmaf(a, wb[j], acc[j]);
    }
    int grow = row0 + r;
    if (grow < NN) {
#pragma unroll
        for (int j = 0; j < 10; j++) g2[(size_t)grow * 40 + g * 10 + j] = acc[j];
    }
    // fused attention dots, reduce over the 4-lane g group
    float ps = 0.f, pd = 0.f;
#pragma unroll
    for (int j = 0; j < 10; j++) {
        ps = fmaf(acc[j], asrc[g * 10 + j], ps);
        pd = fmaf(acc[j], adst[g * 10 + j], pd);
    }
    ps += __shfl_xor(ps, 1); ps += __shfl_xor(ps, 2);
    pd += __shfl_xor(pd, 1); pd += __shfl_xor(pd, 2);
    if (g == 0 && grow < NN) { as2[grow] = ps; ad2[grow] = pd; }
}

// ---- layer2: two-pass segment softmax + gather (wave per node, F=40) --
__global__ __launch_bounds__(256) void k_msg2(const int* __restrict__ row_ptr,
                                              const int2* __restrict__ packed,
                                              const float* __restrict__ as2,
                                              const float* __restrict__ ad2,
                                              const float* __restrict__ g2,
                                              const float* __restrict__ b2,
                                              float* __restrict__ out) {
    int gw = (blockIdx.x * 256 + threadIdx.x) >> 6;
    if (gw >= NN) return;
    const int lane = threadIdx.x & 63;
    const int half = lane >> 5;
    const int fl = lane & 31;
    const bool act = fl < 20;
    const float adv = ad2[gw];
    const int beg = row_ptr[gw], end = row_ptr[gw + 1];

    float m = -INFINITY;
    for (int i = beg + half; i < end; i += 2) {
        unsigned s = (unsigned)packed[(unsigned)i].x;
        m = fmaxf(m, lrelu(as2[s] + adv));
    }
    float M = fmaxf(m, __shfl_xor(m, 32));

    float den = 0.f;
    float2 acc = make_float2(0.f, 0.f);
    for (int i = beg + half; i < end; i += 2) {
        int2 p = packed[(unsigned)i];
        unsigned s = (unsigned)p.x;
        float ex = __expf(lrelu(as2[s] + adv) - M);
        den += ex;
        if (act) {
            float cw = ex * __int_as_float(p.y);
            float2 gv = *(const float2*)(g2 + s * 40u + fl * 2u);
            acc.x = fmaf(gv.x, cw, acc.x);
            acc.y = fmaf(gv.y, cw, acc.y);
        }
    }
    den   += __shfl_xor(den, 32);
    acc.x += __shfl_xor(acc.x, 32);
    acc.y += __shfl_xor(acc.y, 32);
    if (half == 0 && act) {
        float rden = 1.f / (den + 1e-16f);
        float2 bv = *(const float2*)(b2 + fl * 2);
        *(float2*)(out + (unsigned)gw * 40u + fl * 2u) =
            make_float2(acc.x * rden + bv.x, acc.y * rden + bv.y);
    }
}

// ---- host launcher ----------------------------------------------------
extern "C" void kernel_launch(void* const* d_in, const int* in_sizes, int n_in,
                              void* d_out, int out_size, void* d_ws, size_t ws_size,
                              hipStream_t stream) {
    const float* x     = (const float*)d_in[0];
    const int*   ei    = (const int*)d_in[1];
    const float* ew    = (const float*)d_in[2];
    const float* W1    = (const float*)d_in[3];
    const float* at_s1 = (const float*)d_in[4];
    const float* at_d1 = (const float*)d_in[5];
    const float* b1    = (const float*)d_in[6];
    const float* W2    = (const float*)d_in[7];
    const float* at_s2 = (const float*)d_in[8];
    const float* at_d2 = (const float*)d_in[9];
    const float* b2    = (const float*)d_in[10];
    float* out = (float*)d_out;

    const int* src = ei;
    const int* dst = ei + NE;

    // workspace layout; g2 aliases h1 (h1 dead after k_msg1)
    char* w = (char*)d_ws;
    float* h1 = (float*)w;            w += (size_t)NN * 128 * 4;
    float* h2 = (float*)w;            w += (size_t)NN * 128 * 4;
    int2* packed = (int2*)w;          w += (size_t)NE * 8;
    int* pos = (int*)w;               w += (size_t)NE * 4;
    float* as1 = (float*)w;           w += (size_t)NN * 4 * 4;
    float* ad1 = (float*)w;           w += (size_t)NN * 4 * 4;
    float* as2 = (float*)w;           w += (size_t)NN * 4;
    float* ad2 = (float*)w;           w += (size_t)NN * 4;
    int* deg = (int*)w;               w += (size_t)NN * 4;
    int* row_ptr = (int*)w;           w += (size_t)(NN + 1) * 4;
    int* bsum = (int*)w;              w += 512 * 4;
    float* g2 = h1;                   // alias

    // CSR build (rebuilt every call; ws is re-poisoned by harness)
    k_init<<<NBLK_SCAN, 256, 0, stream>>>(deg);
    k_deg<<<3125, 256, 0, stream>>>(dst, deg, pos);
    k_scan1<<<NBLK_SCAN, 256, 0, stream>>>(deg, row_ptr, bsum);
    k_scan2<<<1, 512, 0, stream>>>(bsum);
    k_scan3<<<NBLK_SCAN, 256, 0, stream>>>(row_ptr, bsum);
    k_fill<<<3125, 256, 0, stream>>>(src, dst, ew, row_ptr, pos, packed);

    // layer 1
    k_gemm1<<<dim3(1563, 2), 256, 0, stream>>>(x, W1, at_s1, at_d1, h1, as1, ad1);
    k_msg1<<<25000, 256, 0, stream>>>(row_ptr, packed, as1, ad1, h1, b1, h2);

    // layer 2
    k_gemm2<<<1563, 256, 0, stream>>>(h2, W2, at_s2, at_d2, g2, as2, ad2);
    k_msg2<<<25000, 256, 0, stream>>>(row_ptr, packed, as2, ad2, g2, b2, out);
}

// Round 12
// 539.917 us; speedup vs baseline: 1.2731x; 1.2731x over previous
//
#include <hip/hip_runtime.h>
#include <math.h>

#define NN 100000
#define NE 1600000
#define NBLK_SCAN 391   // ceil(NN/256)

__device__ __forceinline__ float lrelu(float x) { return x > 0.f ? x : 0.2f * x; }

// ---- init: zero degree ------------------------------------------------
__global__ __launch_bounds__(256) void k_init(int* __restrict__ deg) {
    int i = blockIdx.x * 256 + threadIdx.x;
    if (i < NN) deg[i] = 0;
}

// ---- CSR build: histogram (captures position), scan, atomic-free fill --
__global__ __launch_bounds__(256) void k_deg(const int* __restrict__ dst, int* __restrict__ deg,
                                             int* __restrict__ pos) {
    unsigned e = (blockIdx.x * 256 + threadIdx.x) * 2u;
    int2 d2 = *(const int2*)(dst + e);
    int p0 = atomicAdd(&deg[d2.x], 1);
    int p1 = atomicAdd(&deg[d2.y], 1);
    *(int2*)(pos + e) = make_int2(p0, p1);
}

__global__ __launch_bounds__(256) void k_scan1(const int* __restrict__ deg,
                                               int* __restrict__ row_ptr, int* __restrict__ bsum) {
    __shared__ int sm[256];
    int t = threadIdx.x, i = blockIdx.x * 256 + t;
    int v = (i < NN) ? deg[i] : 0;
    sm[t] = v; __syncthreads();
#pragma unroll
    for (int off = 1; off < 256; off <<= 1) {
        int u = (t >= off) ? sm[t - off] : 0;
        __syncthreads();
        sm[t] += u;
        __syncthreads();
    }
    int incl = sm[t];
    if (i < NN) row_ptr[i] = incl - v;
    if (t == 255) bsum[blockIdx.x] = incl;
}

__global__ __launch_bounds__(512) void k_scan2(int* __restrict__ bsum) {
    __shared__ int sm[512];
    int t = threadIdx.x;
    int v = (t < NBLK_SCAN) ? bsum[t] : 0;
    sm[t] = v; __syncthreads();
#pragma unroll
    for (int off = 1; off < 512; off <<= 1) {
        int u = (t >= off) ? sm[t - off] : 0;
        __syncthreads();
        sm[t] += u;
        __syncthreads();
    }
    if (t < NBLK_SCAN) bsum[t] = sm[t] - v;
}

__global__ __launch_bounds__(256) void k_scan3(int* __restrict__ row_ptr, const int* __restrict__ bsum) {
    int i = blockIdx.x * 256 + threadIdx.x;
    if (i < NN) row_ptr[i] += bsum[i >> 8];
    if (i == 0) row_ptr[NN] = NE;
}

__global__ __launch_bounds__(256) void k_fill(const int* __restrict__ src, const int* __restrict__ dst,
                                              const float* __restrict__ ew,
                                              const int* __restrict__ row_ptr,
                                              const int* __restrict__ pos,
                                              int2* __restrict__ packed) {
    unsigned e = (blockIdx.x * 256 + threadIdx.x) * 2u;
    int2 s2 = *(const int2*)(src + e);
    int2 d2 = *(const int2*)(dst + e);
    float2 w2 = *(const float2*)(ew + e);
    int2 po = *(const int2*)(pos + e);
    packed[(unsigned)(row_ptr[d2.x] + po.x)] = make_int2(s2.x, __float_as_int(w2.x));
    packed[(unsigned)(row_ptr[d2.y] + po.y)] = make_int2(s2.y, __float_as_int(w2.y));
}

// ---- GEMM1 + fused layer-1 attention logits ---------------------------
__global__ __launch_bounds__(256) void k_gemm1(const float* __restrict__ x,
                                               const float* __restrict__ W,
                                               const float* __restrict__ asrc,
                                               const float* __restrict__ adst,
                                               float* __restrict__ h1,
                                               float* __restrict__ as1,
                                               float* __restrict__ ad1) {
    __shared__ float xs[128][64];
    __shared__ float ws[128][64];
    const int row0 = blockIdx.x * 64;
    const int col0 = blockIdx.y * 64;
    const int t = threadIdx.x;

    {
        int row = t & 63;
        int grow = row0 + row;
        bool ok = grow < NN;
#pragma unroll
        for (int i = 0; i < 8; i++) {
            int kq = (t >> 6) + i * 4;
            float4 v = ok ? *(const float4*)(x + (size_t)grow * 128 + kq * 4)
                          : make_float4(0.f, 0.f, 0.f, 0.f);
            xs[kq * 4 + 0][row] = v.x;
            xs[kq * 4 + 1][row] = v.y;
            xs[kq * 4 + 2][row] = v.z;
            xs[kq * 4 + 3][row] = v.w;
        }
    }
    {
#pragma unroll
        for (int i = 0; i < 8; i++) {
            int lin = t + i * 256;
            int kk = lin >> 4;
            int cq = lin & 15;
            float4 v = *(const float4*)(W + (size_t)kk * 128 + col0 + cq * 4);
            *(float4*)&ws[kk][cq * 4] = v;
        }
    }
    __syncthreads();

    const int tx = t & 15, ty = t >> 4;
    float acc[4][4] = {};
#pragma unroll 4
    for (int k = 0; k < 128; k++) {
        float4 a4 = *(const float4*)&xs[k][ty * 4];
        float4 b4 = *(const float4*)&ws[k][tx * 4];
        float a[4] = {a4.x, a4.y, a4.z, a4.w};
        float b[4] = {b4.x, b4.y, b4.z, b4.w};
#pragma unroll
        for (int i = 0; i < 4; i++)
#pragma unroll
            for (int j = 0; j < 4; j++)
                acc[i][j] = fmaf(a[i], b[j], acc[i][j]);
    }

#pragma unroll
    for (int i = 0; i < 4; i++) {
        int r = row0 + ty * 4 + i;
        if (r < NN) {
            float4 v = make_float4(acc[i][0], acc[i][1], acc[i][2], acc[i][3]);
            *(float4*)(h1 + (size_t)r * 128 + col0 + tx * 4) = v;
        }
    }

    const int head = (col0 >> 5) + (tx >> 3);
    const float4 avs = *(const float4*)(asrc + head * 32 + (tx & 7) * 4);
    const float4 avd = *(const float4*)(adst + head * 32 + (tx & 7) * 4);
#pragma unroll
    for (int i = 0; i < 4; i++) {
        float ps = acc[i][0] * avs.x + acc[i][1] * avs.y + acc[i][2] * avs.z + acc[i][3] * avs.w;
        float pd = acc[i][0] * avd.x + acc[i][1] * avd.y + acc[i][2] * avd.z + acc[i][3] * avd.w;
        ps += __shfl_xor(ps, 1); ps += __shfl_xor(ps, 2); ps += __shfl_xor(ps, 4);
        pd += __shfl_xor(pd, 1); pd += __shfl_xor(pd, 2); pd += __shfl_xor(pd, 4);
        int r = row0 + ty * 4 + i;
        if ((tx & 7) == 0 && r < NN) {
            as1[(size_t)r * 4 + head] = ps;
            ad1[(size_t)r * 4 + head] = pd;
        }
    }
}

// ---- layer1: wave-parallel max + 4-stream prefetched gather -----------
// Pass A: 16 edge slots x 4 head groups find max(as1) in ~deg/16 iters
//   (lrelu/+adv applied after: both monotone increasing).
// Pass B: 4 streams (q=lane>>4); lane fl=lane&15 owns features fl*8..+7
//   (two float4 = 32B); next edge's packed/as1/h1 prefetched 1-deep.
// Streams merge via shfl_xor(16,32).
__global__ __launch_bounds__(256) void k_msg1(const int* __restrict__ row_ptr,
                                              const int2* __restrict__ packed,
                                              const float* __restrict__ as1,
                                              const float* __restrict__ ad1,
                                              const float* __restrict__ h1,
                                              const float* __restrict__ b1,
                                              float* __restrict__ h2) {
    int gw = (blockIdx.x * 256 + threadIdx.x) >> 6;   // node id
    if (gw >= NN) return;
    const int lane = threadIdx.x & 63;
    const int beg = row_ptr[gw], end = row_ptr[gw + 1];

    // pass A
    float mA = -INFINITY;
    {
        const int el = lane & 15;
        const int hh = lane >> 4;
        for (int i = beg + el; i < end; i += 16)
            mA = fmaxf(mA, as1[(unsigned)packed[(unsigned)i].x * 4u + hh]);
        mA = fmaxf(mA, __shfl_xor(mA, 1));
        mA = fmaxf(mA, __shfl_xor(mA, 2));
        mA = fmaxf(mA, __shfl_xor(mA, 4));
        mA = fmaxf(mA, __shfl_xor(mA, 8));
    }

    // pass B
    const int q = lane >> 4;          // edge stream
    const int fl = lane & 15;         // feature group: floats fl*8..fl*8+7
    const int h = fl >> 2;            // head of these features
    const float adv = ad1[(unsigned)gw * 4u + h];
    const float M = lrelu(__shfl(mA, h << 4) + adv);

    float den = 0.f;
    float4 acc0 = make_float4(0.f, 0.f, 0.f, 0.f);
    float4 acc1 = make_float4(0.f, 0.f, 0.f, 0.f);
    int i = beg + q;
    if (i < end) {
        int2 p = packed[(unsigned)i];
        float av = as1[(unsigned)p.x * 4u + h];
        const float* hp = h1 + (unsigned)p.x * 128u + fl * 8u;
        float4 ha = *(const float4*)hp;
        float4 hb = *(const float4*)(hp + 4);
        while (true) {
            int inext = i + 4;
            bool more = inext < end;
            int2 pn; float avn; float4 han, hbn;
            if (more) {                               // prefetch next edge
                pn = packed[(unsigned)inext];
                avn = as1[(unsigned)pn.x * 4u + h];
                const float* hpn = h1 + (unsigned)pn.x * 128u + fl * 8u;
                han = *(const float4*)hpn;
                hbn = *(const float4*)(hpn + 4);
            }
            float ex = __expf(lrelu(av + adv) - M);
            den += ex;
            float cw = ex * __int_as_float(p.y);
            acc0.x = fmaf(ha.x, cw, acc0.x);
            acc0.y = fmaf(ha.y, cw, acc0.y);
            acc0.z = fmaf(ha.z, cw, acc0.z);
            acc0.w = fmaf(ha.w, cw, acc0.w);
            acc1.x = fmaf(hb.x, cw, acc1.x);
            acc1.y = fmaf(hb.y, cw, acc1.y);
            acc1.z = fmaf(hb.z, cw, acc1.z);
            acc1.w = fmaf(hb.w, cw, acc1.w);
            if (!more) break;
            i = inext; p = pn; av = avn; ha = han; hb = hbn;
        }
    }
    // merge the 4 streams (same fl across q)
#pragma unroll
    for (int d = 16; d <= 32; d <<= 1) {
        den    += __shfl_xor(den, d);
        acc0.x += __shfl_xor(acc0.x, d);
        acc0.y += __shfl_xor(acc0.y, d);
        acc0.z += __shfl_xor(acc0.z, d);
        acc0.w += __shfl_xor(acc0.w, d);
        acc1.x += __shfl_xor(acc1.x, d);
        acc1.y += __shfl_xor(acc1.y, d);
        acc1.z += __shfl_xor(acc1.z, d);
        acc1.w += __shfl_xor(acc1.w, d);
    }
    if (q == 0) {
        float rden = 1.f / (den + 1e-16f);
        float4 b0 = *(const float4*)(b1 + fl * 8);
        float4 b4 = *(const float4*)(b1 + fl * 8 + 4);
        float4 v0, v1;
        v0.x = fmaxf(acc0.x * rden + b0.x, 0.f);
        v0.y = fmaxf(acc0.y * rden + b0.y, 0.f);
        v0.z = fmaxf(acc0.z * rden + b0.z, 0.f);
        v0.w = fmaxf(acc0.w * rden + b0.w, 0.f);
        v1.x = fmaxf(acc1.x * rden + b4.x, 0.f);
        v1.y = fmaxf(acc1.y * rden + b4.y, 0.f);
        v1.z = fmaxf(acc1.z * rden + b4.z, 0.f);
        v1.w = fmaxf(acc1.w * rden + b4.w, 0.f);
        float* op = h2 + (unsigned)gw * 128u + fl * 8u;
        *(float4*)op = v0;
        *(float4*)(op + 4) = v1;
    }
}

// ---- GEMM2 + fused layer-2 attention logits ---------------------------
__global__ __launch_bounds__(256) void k_gemm2(const float* __restrict__ h2,
                                               const float* __restrict__ W2,
                                               const float* __restrict__ asrc,
                                               const float* __restrict__ adst,
                                               float* __restrict__ g2,
                                               float* __restrict__ as2,
                                               float* __restrict__ ad2) {
    __shared__ float xs[128][64];
    __shared__ float ws2[128 * 40];
    const int row0 = blockIdx.x * 64;
    const int t = threadIdx.x;
    {
        int row = t & 63;
        int grow = row0 + row;
        bool ok = grow < NN;
#pragma unroll
        for (int i = 0; i < 8; i++) {
            int kq = (t >> 6) + i * 4;
            float4 v = ok ? *(const float4*)(h2 + (size_t)grow * 128 + kq * 4)
                          : make_float4(0.f, 0.f, 0.f, 0.f);
            xs[kq * 4 + 0][row] = v.x;
            xs[kq * 4 + 1][row] = v.y;
            xs[kq * 4 + 2][row] = v.z;
            xs[kq * 4 + 3][row] = v.w;
        }
    }
    {
#pragma unroll
        for (int i = 0; i < 5; i++) {
            int lin = t + i * 256;
            *(float4*)&ws2[lin * 4] = *(const float4*)(W2 + lin * 4);
        }
    }
    __syncthreads();
    const int g = t & 3, r = t >> 2;
    float acc[10] = {};
#pragma unroll 4
    for (int k = 0; k < 128; k++) {
        float a = xs[k][r];
        const float* wb = &ws2[k * 40 + g * 10];
#pragma unroll
        for (int j = 0; j < 10; j++) acc[j] = fmaf(a, wb[j], acc[j]);
    }
    int grow = row0 + r;
    if (grow < NN) {
#pragma unroll
        for (int j = 0; j < 10; j++) g2[(size_t)grow * 40 + g * 10 + j] = acc[j];
    }
    float ps = 0.f, pd = 0.f;
#pragma unroll
    for (int j = 0; j < 10; j++) {
        ps = fmaf(acc[j], asrc[g * 10 + j], ps);
        pd = fmaf(acc[j], adst[g * 10 + j], pd);
    }
    ps += __shfl_xor(ps, 1); ps += __shfl_xor(ps, 2);
    pd += __shfl_xor(pd, 1); pd += __shfl_xor(pd, 2);
    if (g == 0 && grow < NN) { as2[grow] = ps; ad2[grow] = pd; }
}

// ---- layer2: wave-parallel max + 4-stream prefetched gather (F=40) ----
__global__ __launch_bounds__(256) void k_msg2(const int* __restrict__ row_ptr,
                                              const int2* __restrict__ packed,
                                              const float* __restrict__ as2,
                                              const float* __restrict__ ad2,
                                              const float* __restrict__ g2,
                                              const float* __restrict__ b2,
                                              float* __restrict__ out) {
    int gw = (blockIdx.x * 256 + threadIdx.x) >> 6;
    if (gw >= NN) return;
    const int lane = threadIdx.x & 63;
    const float adv = ad2[gw];
    const int beg = row_ptr[gw], end = row_ptr[gw + 1];

    // pass A: 64-wide max over raw as2 (monotone lrelu/+adv after)
    float mA = -INFINITY;
    for (int i = beg + lane; i < end; i += 64)
        mA = fmaxf(mA, as2[(unsigned)packed[(unsigned)i].x]);
    mA = fmaxf(mA, __shfl_xor(mA, 1));
    mA = fmaxf(mA, __shfl_xor(mA, 2));
    mA = fmaxf(mA, __shfl_xor(mA, 4));
    mA = fmaxf(mA, __shfl_xor(mA, 8));
    mA = fmaxf(mA, __shfl_xor(mA, 16));
    mA = fmaxf(mA, __shfl_xor(mA, 32));
    const float M = lrelu(mA + adv);

    // pass B: 4 streams x 16 lanes; lane fl owns features fl*4..+3 (fl<10)
    const int q = lane >> 4;
    const int fl = lane & 15;
    const bool act = fl < 10;

    float den = 0.f;
    float4 acc = make_float4(0.f, 0.f, 0.f, 0.f);
    int i = beg + q;
    if (i < end) {
        int2 p = packed[(unsigned)i];
        float av = as2[(unsigned)p.x];
        float4 gv = act ? *(const float4*)(g2 + (unsigned)p.x * 40u + fl * 4u)
                        : make_float4(0.f, 0.f, 0.f, 0.f);
        while (true) {
            int inext = i + 4;
            bool more = inext < end;
            int2 pn; float avn; float4 gvn;
            if (more) {
                pn = packed[(unsigned)inext];
                avn = as2[(unsigned)pn.x];
                gvn = act ? *(const float4*)(g2 + (unsigned)pn.x * 40u + fl * 4u)
                          : make_float4(0.f, 0.f, 0.f, 0.f);
            }
            float ex = __expf(lrelu(av + adv) - M);
            den += ex;
            float cw = ex * __int_as_float(p.y);
            acc.x = fmaf(gv.x, cw, acc.x);
            acc.y = fmaf(gv.y, cw, acc.y);
            acc.z = fmaf(gv.z, cw, acc.z);
            acc.w = fmaf(gv.w, cw, acc.w);
            if (!more) break;
            i = inext; p = pn; av = avn; gv = gvn;
        }
    }
#pragma unroll
    for (int d = 16; d <= 32; d <<= 1) {
        den   += __shfl_xor(den, d);
        acc.x += __shfl_xor(acc.x, d);
        acc.y += __shfl_xor(acc.y, d);
        acc.z += __shfl_xor(acc.z, d);
        acc.w += __shfl_xor(acc.w, d);
    }
    if (q == 0 && act) {
        float rden = 1.f / (den + 1e-16f);
        float4 bv = *(const float4*)(b2 + fl * 4);
        float4 v;
        v.x = acc.x * rden + bv.x;
        v.y = acc.y * rden + bv.y;
        v.z = acc.z * rden + bv.z;
        v.w = acc.w * rden + bv.w;
        *(float4*)(out + (unsigned)gw * 40u + fl * 4u) = v;
    }
}

// ---- host launcher ----------------------------------------------------
extern "C" void kernel_launch(void* const* d_in, const int* in_sizes, int n_in,
                              void* d_out, int out_size, void* d_ws, size_t ws_size,
                              hipStream_t stream) {
    const float* x     = (const float*)d_in[0];
    const int*   ei    = (const int*)d_in[1];
    const float* ew    = (const float*)d_in[2];
    const float* W1    = (const float*)d_in[3];
    const float* at_s1 = (const float*)d_in[4];
    const float* at_d1 = (const float*)d_in[5];
    const float* b1    = (const float*)d_in[6];
    const float* W2    = (const float*)d_in[7];
    const float* at_s2 = (const float*)d_in[8];
    const float* at_d2 = (const float*)d_in[9];
    const float* b2    = (const float*)d_in[10];
    float* out = (float*)d_out;

    const int* src = ei;
    const int* dst = ei + NE;

    char* w = (char*)d_ws;
    float* h1 = (float*)w;            w += (size_t)NN * 128 * 4;
    float* h2 = (float*)w;            w += (size_t)NN * 128 * 4;
    int2* packed = (int2*)w;          w += (size_t)NE * 8;
    int* pos = (int*)w;               w += (size_t)NE * 4;
    float* as1 = (float*)w;           w += (size_t)NN * 4 * 4;
    float* ad1 = (float*)w;           w += (size_t)NN * 4 * 4;
    float* as2 = (float*)w;           w += (size_t)NN * 4;
    float* ad2 = (float*)w;           w += (size_t)NN * 4;
    int* deg = (int*)w;               w += (size_t)NN * 4;
    int* row_ptr = (int*)w;           w += (size_t)(NN + 1) * 4;
    int* bsum = (int*)w;              w += 512 * 4;
    float* g2 = h1;                   // alias (h1 dead after k_msg1)

    k_init<<<NBLK_SCAN, 256, 0, stream>>>(deg);
    k_deg<<<3125, 256, 0, stream>>>(dst, deg, pos);
    k_scan1<<<NBLK_SCAN, 256, 0, stream>>>(deg, row_ptr, bsum);
    k_scan2<<<1, 512, 0, stream>>>(bsum);
    k_scan3<<<NBLK_SCAN, 256, 0, stream>>>(row_ptr, bsum);
    k_fill<<<3125, 256, 0, stream>>>(src, dst, ew, row_ptr, pos, packed);

    k_gemm1<<<dim3(1563, 2), 256, 0, stream>>>(x, W1, at_s1, at_d1, h1, as1, ad1);
    k_msg1<<<25000, 256, 0, stream>>>(row_ptr, packed, as1, ad1, h1, b1, h2);

    k_gemm2<<<1563, 256, 0, stream>>>(h2, W2, at_s2, at_d2, g2, as2, ad2);
    k_msg2<<<25000, 256, 0, stream>>>(row_ptr, packed, as2, ad2, g2, b2, out);
}